// Round 1
// baseline (146.561 us; speedup 1.0000x reference)
//
#include <hip/hip_runtime.h>
#include <hip/hip_bf16.h>
#include <math.h>

// Problem: B=1, H=2, S=128, D=64, 2D=128, D*D=4096
// out[h,j,d] = sum_e ( sum_c Hbar[h,j,c]*W2[c, d*64+e] + b2[d*64+e] ) * K[h,j,e]
// Hbar[h,j,c] = (1/S) * sum_i tanh( A[h,i,c] + Bm[h,j,c] + b1[c] )
// A[h,i,c]  = sum_d Q[h,i,d] * W1[d,    c]
// Bm[h,j,c] = sum_e K[h,j,e] * W1[64+e, c]

#define H_ 2
#define S_ 128
#define D_ 64
#define C_ 128  // 2D

// ---------------- Kernel 1: A and Bm (tiny GEMMs) ----------------
// grid: H*S blocks, 128 threads (c). Block b -> (h, r); r serves as both i and j.
__global__ __launch_bounds__(128) void k1_ab(const float* __restrict__ Q,
                                             const float* __restrict__ K,
                                             const float* __restrict__ W1,
                                             float* __restrict__ A,
                                             float* __restrict__ Bm) {
    const int b = blockIdx.x;          // h*128 + r
    const int h = b >> 7;
    const int r = b & 127;
    const int c = threadIdx.x;         // 0..127

    __shared__ float qs[D_];
    __shared__ float ks[D_];
    if (c < 64)       qs[c]      = Q[h*S_*D_ + r*D_ + c];
    else              ks[c - 64] = K[h*S_*D_ + r*D_ + (c - 64)];
    __syncthreads();

    float a = 0.f, bb = 0.f;
#pragma unroll
    for (int d = 0; d < D_; ++d) {
        a  += qs[d] * W1[d*C_ + c];
        bb += ks[d] * W1[(64 + d)*C_ + c];
    }
    A[b*C_ + c]  = a;
    Bm[b*C_ + c] = bb;
}

// ---------------- Kernel 2: Hbar (tanh + mean over i) ----------------
// grid: H*S blocks (h,j), 128 threads (c).
__global__ __launch_bounds__(128) void k2_hbar(const float* __restrict__ A,
                                               const float* __restrict__ Bm,
                                               const float* __restrict__ b1,
                                               float* __restrict__ Hbar) {
    const int blk = blockIdx.x;        // h*128 + j
    const int h = blk >> 7;
    const int c = threadIdx.x;

    const float t = Bm[blk*C_ + c] + b1[c];
    const float* Ah = A + h*S_*C_;
    float acc = 0.f;
#pragma unroll 4
    for (int i = 0; i < S_; ++i) {
        acc += tanhf(Ah[i*C_ + c] + t);
    }
    Hbar[blk*C_ + c] = acc * (1.0f / (float)S_);
}

// ---------------- Kernel 3: fused W2 contraction + K-dot ----------------
// grid: H*D blocks (h,d), 256 threads = 4 waves x 64 lanes (lane = e).
// out[h,j,d] = sum_e ( sum_c Hbar[h,j,c]*W2s[c,e] + b2[d*64+e] ) * K[h,j,e]
__global__ __launch_bounds__(256) void k3_out(const float* __restrict__ K,
                                              const float* __restrict__ W2,
                                              const float* __restrict__ b2,
                                              const float* __restrict__ Hbar,
                                              float* __restrict__ out) {
    const int hd = blockIdx.x;         // 0..127
    const int h = hd >> 6;
    const int d = hd & 63;
    const int tid = threadIdx.x;

    __shared__ float W2s[C_ * D_];     // [c][e], 32 KB
    __shared__ float Hs[S_ * C_];      // [j][c], 64 KB

    // stage W2 column-slice for this d: W2s[c*64+e] = W2[c*4096 + d*64 + e]
    for (int idx = tid; idx < C_ * D_; idx += 256) {
        const int c = idx >> 6;
        const int e = idx & 63;
        W2s[idx] = W2[c*4096 + d*64 + e];
    }
    // stage Hbar for this head
    const float* Hh = Hbar + h*S_*C_;
    for (int idx = tid; idx < S_ * C_; idx += 256) {
        Hs[idx] = Hh[idx];
    }
    __syncthreads();

    const int e = tid & 63;            // lane
    const int w = tid >> 6;            // wave 0..3
    const float b2v = b2[d*64 + e];
    const float* Kh = K + h*S_*D_;

    // wave w handles j in [w*32, w*32+32), blocked by 4
    for (int j0 = w*32; j0 < w*32 + 32; j0 += 4) {
        float acc0 = 0.f, acc1 = 0.f, acc2 = 0.f, acc3 = 0.f;
        const float4* r0 = (const float4*)&Hs[(j0 + 0)*C_];
        const float4* r1 = (const float4*)&Hs[(j0 + 1)*C_];
        const float4* r2 = (const float4*)&Hs[(j0 + 2)*C_];
        const float4* r3 = (const float4*)&Hs[(j0 + 3)*C_];
#pragma unroll 8
        for (int c4 = 0; c4 < C_ / 4; ++c4) {
            const float4 h0 = r0[c4];
            const float4 h1 = r1[c4];
            const float4 h2 = r2[c4];
            const float4 h3 = r3[c4];
            const float w0 = W2s[(c4*4 + 0)*64 + e];
            const float w1 = W2s[(c4*4 + 1)*64 + e];
            const float w2v = W2s[(c4*4 + 2)*64 + e];
            const float w3 = W2s[(c4*4 + 3)*64 + e];
            acc0 += h0.x*w0 + h0.y*w1 + h0.z*w2v + h0.w*w3;
            acc1 += h1.x*w0 + h1.y*w1 + h1.z*w2v + h1.w*w3;
            acc2 += h2.x*w0 + h2.y*w1 + h2.z*w2v + h2.w*w3;
            acc3 += h3.x*w0 + h3.y*w1 + h3.z*w2v + h3.w*w3;
        }
        float vals[4] = {acc0, acc1, acc2, acc3};
#pragma unroll
        for (int jj = 0; jj < 4; ++jj) {
            float v = (vals[jj] + b2v) * Kh[(j0 + jj)*D_ + e];
            // wave-wide (64 lane) reduction over e
            for (int off = 32; off > 0; off >>= 1)
                v += __shfl_down(v, off);
            if (e == 0)
                out[h*S_*D_ + (j0 + jj)*D_ + d] = v;
        }
    }
}

extern "C" void kernel_launch(void* const* d_in, const int* in_sizes, int n_in,
                              void* d_out, int out_size, void* d_ws, size_t ws_size,
                              hipStream_t stream) {
    const float* Q  = (const float*)d_in[0];   // [1,2,128,64]
    const float* K  = (const float*)d_in[1];   // [1,2,128,64]
    const float* W1 = (const float*)d_in[2];   // [128,128]
    const float* b1 = (const float*)d_in[3];   // [128]
    const float* W2 = (const float*)d_in[4];   // [128,4096]
    const float* b2 = (const float*)d_in[5];   // [4096]
    float* out = (float*)d_out;                // [1,2,128,64]

    float* A    = (float*)d_ws;                // [2,128,128]
    float* Bm   = A  + H_*S_*C_;               // [2,128,128]
    float* Hbar = Bm + H_*S_*C_;               // [2,128,128]

    k1_ab  <<<H_*S_, 128, 0, stream>>>(Q, K, W1, A, Bm);
    k2_hbar<<<H_*S_, 128, 0, stream>>>(A, Bm, b1, Hbar);
    k3_out <<<H_*D_, 256, 0, stream>>>(K, W2, b2, Hbar, out);
}

// Round 2
// 111.632 us; speedup vs baseline: 1.3129x; 1.3129x over previous
//
#include <hip/hip_runtime.h>
#include <hip/hip_bf16.h>
#include <math.h>

// Problem: B=1, H=2, S=128, D=64, 2D=128, D*D=4096
// out[h,j,d] = sum_e ( sum_c Hbar[h,j,c]*W2[c, d*64+e] + b2[d*64+e] ) * K[h,j,e]
// Hbar[h,j,c] = (1/S) * sum_i tanh( A[h,i,c] + Bm[h,j,c] + b1[c] )
// A[h,i,c]  = sum_d Q[h,i,d] * W1[d,    c]
// Bm[h,j,c] = sum_e K[h,j,e] * W1[64+e, c]

#define H_ 2
#define S_ 128
#define D_ 64
#define C_ 128  // 2D

// fast tanh: 1 - 2/(exp(2x)+1). v_exp_f32 + v_rcp_f32, ~1e-6 abs error.
// Saturates correctly: x>>0 -> exp=inf -> rcp=0 -> 1; x<<0 -> exp=0 -> -1.
__device__ __forceinline__ float ftanh(float x) {
    float e2 = __expf(2.0f * x);
    return 1.0f - 2.0f * __builtin_amdgcn_rcpf(e2 + 1.0f);
}

// ---------------- Kernel 1: A and Bm (tiny GEMMs) ----------------
// grid: H*S blocks, 128 threads (c). Block b -> (h, r); r serves as both i and j.
__global__ __launch_bounds__(128) void k1_ab(const float* __restrict__ Q,
                                             const float* __restrict__ K,
                                             const float* __restrict__ W1,
                                             float* __restrict__ A,
                                             float* __restrict__ Bm) {
    const int b = blockIdx.x;          // h*128 + r
    const int h = b >> 7;
    const int r = b & 127;
    const int c = threadIdx.x;         // 0..127

    __shared__ float qs[D_];
    __shared__ float ks[D_];
    if (c < 64)       qs[c]      = Q[h*S_*D_ + r*D_ + c];
    else              ks[c - 64] = K[h*S_*D_ + r*D_ + (c - 64)];
    __syncthreads();

    float a = 0.f, bb = 0.f;
#pragma unroll
    for (int d = 0; d < D_; ++d) {
        a  += qs[d] * W1[d*C_ + c];
        bb += ks[d] * W1[(64 + d)*C_ + c];
    }
    A[b*C_ + c]  = a;
    Bm[b*C_ + c] = bb;
}

// ---------------- Kernel 2: Hbar (fast tanh + mean over i) ----------------
// grid: H*S blocks (h,j), 256 threads: c = tid&127, i-half = tid>>7.
__global__ __launch_bounds__(256) void k2_hbar(const float* __restrict__ A,
                                               const float* __restrict__ Bm,
                                               const float* __restrict__ b1,
                                               float* __restrict__ Hbar) {
    const int blk = blockIdx.x;        // h*128 + j
    const int h = blk >> 7;
    const int c = threadIdx.x & 127;
    const int half = threadIdx.x >> 7;

    const float t = Bm[blk*C_ + c] + b1[c];
    const float* Ah = A + h*S_*C_ + half*64*C_;
    float acc = 0.f;
#pragma unroll 8
    for (int i = 0; i < 64; ++i) {
        acc += ftanh(Ah[i*C_ + c] + t);
    }

    __shared__ float red[C_];
    if (half == 0) red[c] = acc;
    __syncthreads();
    if (half == 1) {
        Hbar[blk*C_ + c] = (acc + red[c]) * (1.0f / (float)S_);
    }
}

// ---------------- Kernel 3: fused W2 contraction + K-dot ----------------
// grid: H*D*2 blocks -> (h, d, j-half). 256 threads = 4 waves; lane = e.
// Wave w handles 16 j's: j = jh*64 + w*16 + [0,16).
// Hbar rows are read via wave-uniform (scalar) loads; W2 d-slice staged in LDS.
__global__ __launch_bounds__(256) void k3_out(const float* __restrict__ K,
                                              const float* __restrict__ W2,
                                              const float* __restrict__ b2,
                                              const float* __restrict__ Hbar,
                                              float* __restrict__ out) {
    const int b = blockIdx.x;          // 0..255
    const int h  = b >> 7;
    const int d  = (b >> 1) & 63;
    const int jh = b & 1;
    const int tid = threadIdx.x;
    const int lane = tid & 63;         // e

    __shared__ float W2s[C_ * D_];     // [c][e], 32 KB

    // stage W2 column-slice for this d: W2s[c*64+e] = W2[c*4096 + d*64 + e]
    // float4: 8192 floats = 2048 float4, 256 threads -> 8 iters.
    {
        const float4* src = (const float4*)(W2 + d*64);
#pragma unroll
        for (int it = 0; it < 8; ++it) {
            const int idx = it*256 + tid;      // float4 index into W2s
            const int c   = idx >> 4;          // 16 float4 per c-row
            const int e4  = idx & 15;
            ((float4*)W2s)[idx] = src[c*1024 + e4];  // 4096/4 = 1024 float4 per W2 row
        }
    }
    __syncthreads();

    // force wave-uniform j-base so Hbar loads go through the scalar pipe
    const int w = __builtin_amdgcn_readfirstlane(tid >> 6);
    const int jbase = jh*64 + w*16;

    const float b2v = b2[d*64 + lane];
    const float* __restrict__ Hrow = Hbar + (h*S_ + jbase)*C_;

    float acc[16];
#pragma unroll
    for (int jj = 0; jj < 16; ++jj) acc[jj] = 0.f;

#pragma unroll 4
    for (int c4 = 0; c4 < C_/4; ++c4) {
        const float w0 = W2s[(c4*4 + 0)*64 + lane];
        const float w1 = W2s[(c4*4 + 1)*64 + lane];
        const float w2v = W2s[(c4*4 + 2)*64 + lane];
        const float w3 = W2s[(c4*4 + 3)*64 + lane];
#pragma unroll
        for (int jj = 0; jj < 16; ++jj) {
            const float4 hv = *(const float4*)&Hrow[jj*C_ + c4*4];  // uniform -> s_load
            acc[jj] += hv.x*w0 + hv.y*w1 + hv.z*w2v + hv.w*w3;
        }
    }

    const float* Kh = K + h*S_*D_;
#pragma unroll
    for (int jj = 0; jj < 16; ++jj) {
        const int j = jbase + jj;
        float v = (acc[jj] + b2v) * Kh[j*D_ + lane];
#pragma unroll
        for (int off = 32; off > 0; off >>= 1)
            v += __shfl_down(v, off);
        if (lane == 0)
            out[h*S_*D_ + j*D_ + d] = v;
    }
}

extern "C" void kernel_launch(void* const* d_in, const int* in_sizes, int n_in,
                              void* d_out, int out_size, void* d_ws, size_t ws_size,
                              hipStream_t stream) {
    const float* Q  = (const float*)d_in[0];   // [1,2,128,64]
    const float* K  = (const float*)d_in[1];   // [1,2,128,64]
    const float* W1 = (const float*)d_in[2];   // [128,128]
    const float* b1 = (const float*)d_in[3];   // [128]
    const float* W2 = (const float*)d_in[4];   // [128,4096]
    const float* b2 = (const float*)d_in[5];   // [4096]
    float* out = (float*)d_out;                // [1,2,128,64]

    float* A    = (float*)d_ws;                // [2,128,128]
    float* Bm   = A  + H_*S_*C_;               // [2,128,128]
    float* Hbar = Bm + H_*S_*C_;               // [2,128,128]

    k1_ab  <<<H_*S_,   128, 0, stream>>>(Q, K, W1, A, Bm);
    k2_hbar<<<H_*S_,   256, 0, stream>>>(A, Bm, b1, Hbar);
    k3_out <<<H_*D_*2, 256, 0, stream>>>(K, W2, b2, Hbar, out);
}

// Round 3
// 97.400 us; speedup vs baseline: 1.5047x; 1.1461x over previous
//
#include <hip/hip_runtime.h>
#include <hip/hip_bf16.h>
#include <math.h>

// Problem: B=1, H=2, S=128, D=64, 2D=128, D*D=4096
// out[h,j,d] = sum_e ( sum_c Hbar[h,j,c]*W2[c, d*64+e] + b2[d*64+e] ) * K[h,j,e]
// Hbar[h,j,c] = (1/S) * sum_i tanh( A[h,i,c] + Bm[h,j,c] + b1[c] )
// A[h,i,c]  = sum_d Q[h,i,d] * W1[d,    c]
// Bm[h,j,c] = sum_e K[h,j,e] * W1[64+e, c]

#define H_ 2
#define S_ 128
#define D_ 64
#define C_ 128  // 2D

// fast tanh: 1 - 2/(exp(2x)+1). v_exp_f32 + v_rcp_f32, ~1e-6 abs error.
__device__ __forceinline__ float ftanh(float x) {
    float e2 = __expf(2.0f * x);
    return 1.0f - 2.0f * __builtin_amdgcn_rcpf(e2 + 1.0f);
}

// ---------------- Kernel 1: A and Bm (tiny GEMMs) ----------------
// grid: H*S blocks, 128 threads (c). Block b -> (h, r); r serves as both i and j.
__global__ __launch_bounds__(128) void k1_ab(const float* __restrict__ Q,
                                             const float* __restrict__ K,
                                             const float* __restrict__ W1,
                                             float* __restrict__ A,
                                             float* __restrict__ Bm) {
    const int b = blockIdx.x;          // h*128 + r
    const int h = b >> 7;
    const int r = b & 127;
    const int c = threadIdx.x;         // 0..127

    __shared__ float qs[D_];
    __shared__ float ks[D_];
    if (c < 64)       qs[c]      = Q[h*S_*D_ + r*D_ + c];
    else              ks[c - 64] = K[h*S_*D_ + r*D_ + (c - 64)];
    __syncthreads();

    float a = 0.f, bb = 0.f;
#pragma unroll
    for (int d = 0; d < D_; ++d) {
        a  += qs[d] * W1[d*C_ + c];
        bb += ks[d] * W1[(64 + d)*C_ + c];
    }
    A[b*C_ + c]  = a;
    Bm[b*C_ + c] = bb;
}

// ---------------- Kernel 2: Hbar (fast tanh + mean over i) ----------------
// grid: H*S blocks (h,j), 512 threads: c = tid&127, i-quarter = tid>>7.
__global__ __launch_bounds__(512) void k2_hbar(const float* __restrict__ A,
                                               const float* __restrict__ Bm,
                                               const float* __restrict__ b1,
                                               float* __restrict__ Hbar) {
    const int blk = blockIdx.x;        // h*128 + j
    const int h = blk >> 7;
    const int tid = threadIdx.x;
    const int c = tid & 127;
    const int q = tid >> 7;            // 0..3

    const float t = Bm[blk*C_ + c] + b1[c];
    const float* Ah = A + h*S_*C_ + q*32*C_;
    float acc = 0.f;
#pragma unroll 8
    for (int i = 0; i < 32; ++i) {
        acc += ftanh(Ah[i*C_ + c] + t);
    }

    __shared__ float red[512];
    red[tid] = acc;
    __syncthreads();
    if (q == 0) {
        Hbar[blk*C_ + c] = (red[c] + red[c + 128] + red[c + 256] + red[c + 384])
                           * (1.0f / (float)S_);
    }
}

// ---------------- Kernel 3: fused W2 contraction + K-dot ----------------
// grid: H*D*2 blocks -> (h, d, j-half). 256 threads = 4 waves; lane = e.
// Wave w handles 16 j's. W2 column slice lives in VGPRs (loaded once,
// coalesced); Hbar rows are wave-uniform -> s_load; NO LDS in the main loop
// so scalar loads pipeline freely. Shuffle reductions deferred to epilogue.
__global__ __launch_bounds__(256) void k3_out(const float* __restrict__ K,
                                              const float* __restrict__ W2,
                                              const float* __restrict__ b2,
                                              const float* __restrict__ Hbar,
                                              float* __restrict__ out) {
    const int b = blockIdx.x;          // 0..255
    const int h  = b >> 7;
    const int d  = (b >> 1) & 63;
    const int jh = b & 1;
    const int lane = threadIdx.x & 63;     // e
    const int w = __builtin_amdgcn_readfirstlane(threadIdx.x >> 6);
    const int jbase = jh*64 + w*16;

    // W2 column slice for this (d, e): 128 floats in VGPRs, coalesced loads.
    float w2reg[C_];
#pragma unroll
    for (int c = 0; c < C_; ++c) {
        w2reg[c] = W2[c*4096 + d*64 + lane];
    }

    // K values for this lane's e across the wave's 16 j's.
    float kv[16];
#pragma unroll
    for (int jj = 0; jj < 16; ++jj) {
        kv[jj] = K[(h*S_ + jbase + jj)*D_ + lane];
    }
    const float b2v = b2[d*64 + lane];

    // Main loop: pure SMEM (uniform Hbar rows) + VALU. No DS ops here.
    const float* __restrict__ Hbase = Hbar + (h*S_ + jbase)*C_;
    float acc[16];
#pragma unroll
    for (int jj = 0; jj < 16; ++jj) {
        const float* __restrict__ Hrow = Hbase + jj*C_;  // wave-uniform
        float t0 = 0.f, t1 = 0.f, t2 = 0.f, t3 = 0.f;
#pragma unroll
        for (int c = 0; c < C_; c += 4) {
            t0 += Hrow[c + 0] * w2reg[c + 0];
            t1 += Hrow[c + 1] * w2reg[c + 1];
            t2 += Hrow[c + 2] * w2reg[c + 2];
            t3 += Hrow[c + 3] * w2reg[c + 3];
        }
        acc[jj] = (t0 + t1) + (t2 + t3);
    }

    // Epilogue: (acc + b2)*K, reduce over e (64 lanes), write out.
#pragma unroll
    for (int jj = 0; jj < 16; ++jj) {
        float v = (acc[jj] + b2v) * kv[jj];
#pragma unroll
        for (int off = 32; off > 0; off >>= 1)
            v += __shfl_down(v, off);
        if (lane == 0)
            out[h*S_*D_ + (jbase + jj)*D_ + d] = v;
    }
}

extern "C" void kernel_launch(void* const* d_in, const int* in_sizes, int n_in,
                              void* d_out, int out_size, void* d_ws, size_t ws_size,
                              hipStream_t stream) {
    const float* Q  = (const float*)d_in[0];   // [1,2,128,64]
    const float* K  = (const float*)d_in[1];   // [1,2,128,64]
    const float* W1 = (const float*)d_in[2];   // [128,128]
    const float* b1 = (const float*)d_in[3];   // [128]
    const float* W2 = (const float*)d_in[4];   // [128,4096]
    const float* b2 = (const float*)d_in[5];   // [4096]
    float* out = (float*)d_out;                // [1,2,128,64]

    float* A    = (float*)d_ws;                // [2,128,128]
    float* Bm   = A  + H_*S_*C_;               // [2,128,128]
    float* Hbar = Bm + H_*S_*C_;               // [2,128,128]

    k1_ab  <<<H_*S_,   128, 0, stream>>>(Q, K, W1, A, Bm);
    k2_hbar<<<H_*S_,   512, 0, stream>>>(A, Bm, b1, Hbar);
    k3_out <<<H_*D_*2, 256, 0, stream>>>(K, W2, b2, Hbar, out);
}

// Round 5
// 94.566 us; speedup vs baseline: 1.5498x; 1.0300x over previous
//
#include <hip/hip_runtime.h>
#include <hip/hip_bf16.h>
#include <math.h>

// Problem: B=1, H=2, S=128, D=64, 2D=128, D*D=4096
// out[h,j,d] = sum_e ( sum_c Hbar[h,j,c]*W2[c, d*64+e] + b2[d*64+e] ) * K[h,j,e]
// Hbar[h,j,c] = (1/S) * sum_i tanh( A[h,i,c] + Bm[h,j,c] + b1[c] )
// A[h,i,c]  = sum_d Q[h,i,d] * W1[d,    c]
// Bm[h,j,c] = sum_e K[h,j,e] * W1[64+e, c]

#define H_ 2
#define S_ 128
#define D_ 64
#define C_ 128  // 2D

// fast tanh: 1 - 2/(exp(2x)+1). v_exp_f32 + v_rcp_f32, ~1e-6 abs error.
// Saturates correctly at +/-1 for large |x|.
__device__ __forceinline__ float ftanh(float x) {
    float e2 = __expf(2.0f * x);
    return 1.0f - 2.0f * __builtin_amdgcn_rcpf(e2 + 1.0f);
}

// ---------------- Kernel 1+2 fused: Hbar, decomposed by (h, c) ----------------
// Block b = (h, c). The block computes the full column A[h,:,c], Bm[h,:,c]+b1[c]
// into LDS (no global A/Bm at all), then the 128x128 tanh-mean for column c.
// W1 column reads are block-uniform -> scalar pipe; As reads are LDS broadcast.
__global__ __launch_bounds__(256) void k12_hbar(const float* __restrict__ Q,
                                                const float* __restrict__ K,
                                                const float* __restrict__ W1,
                                                const float* __restrict__ b1,
                                                float* __restrict__ Hbar) {
    const int b = blockIdx.x;          // h*128 + c
    const int h = b >> 7;
    const int c = b & 127;
    const int tid = threadIdx.x;

    __shared__ float As[S_];           // A[h, i, c]
    __shared__ float Bs[S_];           // Bm[h, j, c] + b1[c]
    __shared__ float red[256];

    // Step 1: waves 0-1 compute As (from Q), waves 2-3 compute Bs (from K).
    {
        const int r   = tid & 127;     // i (sel=0) or j (sel=1)
        const int sel = tid >> 7;      // wave-uniform
        const float* __restrict__ src = sel ? K : Q;
        const float* __restrict__ w1col = W1 + sel*64*C_ + c;  // W1[sel*64+d][c]
        const float4* __restrict__ row = (const float4*)(src + (h*S_ + r)*D_);
        float acc = 0.f;
#pragma unroll
        for (int d4 = 0; d4 < D_/4; ++d4) {
            const float4 v = row[d4];
            acc += v.x * w1col[(4*d4 + 0)*C_]
                 + v.y * w1col[(4*d4 + 1)*C_]
                 + v.z * w1col[(4*d4 + 2)*C_]
                 + v.w * w1col[(4*d4 + 3)*C_];
        }
        if (sel == 0) As[r] = acc;
        else          Bs[r] = acc + b1[c];
    }
    __syncthreads();

    // Step 2: thread (j, q) sums tanh over its 64 i's. As[i] is an LDS
    // broadcast (same address across the wave) -> conflict-free.
    {
        const int j = tid & 127, q = tid >> 7;
        const float t = Bs[j];
        const float* __restrict__ Aq = As + q*64;
        float acc = 0.f;
#pragma unroll 8
        for (int i = 0; i < 64; ++i)
            acc += ftanh(Aq[i] + t);
        red[tid] = acc;
    }
    __syncthreads();

    if (tid < 128) {
        Hbar[(h*S_ + tid)*C_ + c] = (red[tid] + red[tid + 128]) * (1.0f/128.f);
    }
}

// ---------------- Kernel 3: fused W2 contraction + K-dot ----------------
// grid: H*D*2 blocks -> (h, d, j-half). 256 threads = 4 waves; lane = e.
// Wave w handles 16 j's. W2 column slice lives in VGPRs (loaded once,
// coalesced); Hbar rows are wave-uniform -> scalar loads; no LDS in the
// main loop. Shuffle reductions deferred to the epilogue.
__global__ __launch_bounds__(256) void k3_out(const float* __restrict__ K,
                                              const float* __restrict__ W2,
                                              const float* __restrict__ b2,
                                              const float* __restrict__ Hbar,
                                              float* __restrict__ out) {
    const int b = blockIdx.x;          // 0..255
    const int h  = b >> 7;
    const int d  = (b >> 1) & 63;
    const int jh = b & 1;
    const int lane = threadIdx.x & 63;     // e
    const int w = __builtin_amdgcn_readfirstlane(threadIdx.x >> 6);
    const int jbase = jh*64 + w*16;

    // W2 column slice for this (d, e): 128 floats in VGPRs, coalesced loads.
    float w2reg[C_];
#pragma unroll
    for (int c = 0; c < C_; ++c) {
        w2reg[c] = W2[c*4096 + d*64 + lane];
    }

    // K values for this lane's e across the wave's 16 j's.
    float kv[16];
#pragma unroll
    for (int jj = 0; jj < 16; ++jj) {
        kv[jj] = K[(h*S_ + jbase + jj)*D_ + lane];
    }
    const float b2v = b2[d*64 + lane];

    // Main loop: uniform Hbar rows (scalar pipe) + VALU only.
    const float* __restrict__ Hbase = Hbar + (h*S_ + jbase)*C_;
    float acc[16];
#pragma unroll
    for (int jj = 0; jj < 16; ++jj) {
        const float* __restrict__ Hrow = Hbase + jj*C_;  // wave-uniform
        float t0 = 0.f, t1 = 0.f, t2 = 0.f, t3 = 0.f;
#pragma unroll
        for (int c = 0; c < C_; c += 4) {
            t0 += Hrow[c + 0] * w2reg[c + 0];
            t1 += Hrow[c + 1] * w2reg[c + 1];
            t2 += Hrow[c + 2] * w2reg[c + 2];
            t3 += Hrow[c + 3] * w2reg[c + 3];
        }
        acc[jj] = (t0 + t1) + (t2 + t3);
    }

    // Epilogue: (acc + b2)*K, reduce over e (64 lanes), write out.
#pragma unroll
    for (int jj = 0; jj < 16; ++jj) {
        float v = (acc[jj] + b2v) * kv[jj];
#pragma unroll
        for (int off = 32; off > 0; off >>= 1)
            v += __shfl_down(v, off);
        if (lane == 0)
            out[h*S_*D_ + (jbase + jj)*D_ + d] = v;
    }
}

extern "C" void kernel_launch(void* const* d_in, const int* in_sizes, int n_in,
                              void* d_out, int out_size, void* d_ws, size_t ws_size,
                              hipStream_t stream) {
    const float* Q  = (const float*)d_in[0];   // [1,2,128,64]
    const float* K  = (const float*)d_in[1];   // [1,2,128,64]
    const float* W1 = (const float*)d_in[2];   // [128,128]
    const float* b1 = (const float*)d_in[3];   // [128]
    const float* W2 = (const float*)d_in[4];   // [128,4096]
    const float* b2 = (const float*)d_in[5];   // [4096]
    float* out = (float*)d_out;                // [1,2,128,64]

    float* Hbar = (float*)d_ws;                // [2,128,128]

    k12_hbar<<<H_*S_,   256, 0, stream>>>(Q, K, W1, b1, Hbar);
    k3_out  <<<H_*D_*2, 256, 0, stream>>>(K, W2, b2, Hbar, out);
}